// Round 2
// 128.385 us; speedup vs baseline: 1.0347x; 1.0347x over previous
//
#include <hip/hip_runtime.h>
#include <math.h>
#include <cstddef>

// Shapes fixed by setup_inputs()
#define B_  16
#define T2_ 2048
#define T1_ 512
#define F_  128

constexpr float DELTA_C  = 10.0f;
constexpr float EPS_C    = 1e-8f;
constexpr float THRESH_C = 0.9f;
constexpr float STEEP_C  = 10.0f;

typedef float f4v __attribute__((ext_vector_type(4)));

// --- K1 (fused): activity + imv_proposal.
// v2: 4 rows per wave, 16 lanes per row. Reduction is 4 butterfly levels
// shared across rows -> 4 DS ops/row instead of 24; per-row overhead /4.
// alpha streamed once -> nontemporal keeps it out of L2 (mels stays cached).
__global__ __launch_bounds__(256) void actprop_kernel(const float* __restrict__ mels,
                                                      const float* __restrict__ alpha,
                                                      const int* __restrict__ mel_mask,
                                                      float* __restrict__ act,
                                                      float* __restrict__ prop) {
    int wv   = (int)((blockIdx.x * blockDim.x + threadIdx.x) >> 6);
    int lane = threadIdx.x & 63;
    int il   = lane & 15;               // lane within 16-lane row group
    int r    = wv * 4 + (lane >> 4);    // grid sized exactly: r < B_*T2_
    int t    = r & (T2_ - 1);           // T2 is a power of two

    // alpha row: 512 floats = 128 f4v; 16 lanes x 8 chunks, 256B/row/instr
    const f4v* arow = (const f4v*)(alpha + (size_t)r * T1_);
    f4v a0 = __builtin_nontemporal_load(&arow[il]);
    f4v a1 = __builtin_nontemporal_load(&arow[il + 16]);
    f4v a2 = __builtin_nontemporal_load(&arow[il + 32]);
    f4v a3 = __builtin_nontemporal_load(&arow[il + 48]);
    f4v a4 = __builtin_nontemporal_load(&arow[il + 64]);
    f4v a5 = __builtin_nontemporal_load(&arow[il + 80]);
    f4v a6 = __builtin_nontemporal_load(&arow[il + 96]);
    f4v a7 = __builtin_nontemporal_load(&arow[il + 112]);

    // mels rows t and t-1 (t==0: load own row, result unused)
    int rm = (t == 0) ? r : (r - 1);
    const f4v* my = (const f4v*)(mels + (size_t)r  * F_);
    const f4v* mx = (const f4v*)(mels + (size_t)rm * F_);
    f4v y0 = my[il * 2], y1 = my[il * 2 + 1];
    f4v x0 = mx[il * 2], x1 = mx[il * 2 + 1];

    float d  = x0.x*y0.x + x0.y*y0.y + x0.z*y0.z + x0.w*y0.w
             + x1.x*y1.x + x1.y*y1.y + x1.z*y1.z + x1.w*y1.w;
    float n0 = x0.x*x0.x + x0.y*x0.y + x0.z*x0.z + x0.w*x0.w
             + x1.x*x1.x + x1.y*x1.y + x1.z*x1.z + x1.w*x1.w;
    float n1 = y0.x*y0.x + y0.y*y0.y + y0.z*y0.z + y0.w*y0.w
             + y1.x*y1.x + y1.y*y1.y + y1.z*y1.z + y1.w*y1.w;

    // psum = sum_s alpha[s]*s ; chunk c covers floats il*4 + 64c .. +3
    float fb = (float)(il * 4);
    float psum;
    psum  = a0.x*(fb      ) + a0.y*(fb +   1.f) + a0.z*(fb +   2.f) + a0.w*(fb +   3.f);
    psum += a1.x*(fb+ 64.f) + a1.y*(fb +  65.f) + a1.z*(fb +  66.f) + a1.w*(fb +  67.f);
    psum += a2.x*(fb+128.f) + a2.y*(fb + 129.f) + a2.z*(fb + 130.f) + a2.w*(fb + 131.f);
    psum += a3.x*(fb+192.f) + a3.y*(fb + 193.f) + a3.z*(fb + 194.f) + a3.w*(fb + 195.f);
    psum += a4.x*(fb+256.f) + a4.y*(fb + 257.f) + a4.z*(fb + 258.f) + a4.w*(fb + 259.f);
    psum += a5.x*(fb+320.f) + a5.y*(fb + 321.f) + a5.z*(fb + 322.f) + a5.w*(fb + 323.f);
    psum += a6.x*(fb+384.f) + a6.y*(fb + 385.f) + a6.z*(fb + 386.f) + a6.w*(fb + 387.f);
    psum += a7.x*(fb+448.f) + a7.y*(fb + 449.f) + a7.z*(fb + 450.f) + a7.w*(fb + 451.f);

    // 16-lane group reduction (xor 8,4,2,1 stays within the group)
    for (int off = 8; off > 0; off >>= 1) {
        psum += __shfl_xor(psum, off, 64);
        d    += __shfl_xor(d,    off, 64);
        n0   += __shfl_xor(n0,   off, 64);
        n1   += __shfl_xor(n1,   off, 64);
    }

    if (il == 0) {
        float a_val;
        if (t == 0) {
            a_val = 1.0f;
        } else {
            float cs = d / (fmaxf(sqrtf(n0), 1e-12f) * fmaxf(sqrtf(n1), 1e-12f));
            a_val = 1.0f / (1.0f + __expf(-STEEP_C * (THRESH_C - cs)));
        }
        act[r]  = a_val * (float)mel_mask[r];
        prop[r] = psum;
    }
}

// --- K2: per batch: eff_delta -> wave-shuffle scan -> rescale -> imv,
//     packed {key, am/Z}, and per-phoneme band bounds via LDS binary search.
// v2: 512 threads (4 t's each, half the serial chain; 1 search per thread).
__global__ __launch_bounds__(512) void scan_kernel(const float* __restrict__ prop,
                                                   const float* __restrict__ act,
                                                   const int* __restrict__ mel_mask,
                                                   const int* __restrict__ text_mask,
                                                   float* __restrict__ imv_out,
                                                   float2* __restrict__ packed,
                                                   int2* __restrict__ bounds) {
    int b    = blockIdx.x;
    int tid  = threadIdx.x;            // 512 threads, 4 t's each
    int wave = tid >> 6, lane = tid & 63;
    __shared__ float s_imv[T2_];       // later overwritten with search keys
    __shared__ float s_wsum[8];
    __shared__ int   s_am8[8], s_tm8[8];
    __shared__ int   s_tm[T1_];

    const float* pr = prop + (size_t)b * T2_;
    const float* ac = act  + (size_t)b * T2_;
    const int*   mm = mel_mask  + (size_t)b * T2_;
    const int*   tm = text_mask + (size_t)b * T1_;

    int tmv = tm[tid];
    s_tm[tid] = tmv;

    float e[4];
    int   mmv[4];
    int t0 = tid * 4;
    int am_local = 0;
    float run = 0.0f;
    for (int i = 0; i < 4; i++) {
        int t = t0 + i;
        float dd = (t == 0) ? 0.0f : (pr[t] - pr[t - 1]) * ac[t];
        dd = fminf(fmaxf(dd, 0.0f), 1.0f);
        run += dd;
        e[i] = run;
        mmv[i] = mm[t];
        am_local += mmv[i];
    }
    int tm_local = tmv;
    for (int off = 32; off > 0; off >>= 1) {
        am_local += __shfl_xor(am_local, off, 64);
        tm_local += __shfl_xor(tm_local, off, 64);
    }
    if (lane == 0) { s_am8[wave] = am_local; s_tm8[wave] = tm_local; }

    // wave-level inclusive scan of per-thread totals
    float v = run;
    for (int off = 1; off < 64; off <<= 1) {
        float u = __shfl_up(v, off, 64);
        if (lane >= off) v += u;
    }
    if (lane == 63) s_wsum[wave] = v;
    __syncthreads();                                    // B1

    float woff = 0.0f;
    for (int w = 0; w < 8; w++) woff += (w < wave) ? s_wsum[w] : 0.0f;
    float excl = woff + v - run;
    for (int i = 0; i < 4; i++) {
        int t = t0 + i;
        s_imv[t] = (e[i] + excl) * (float)mmv[i];
    }
    __syncthreads();                                    // B2

    int am_total = 0, tm_total = 0;
    for (int w = 0; w < 8; w++) { am_total += s_am8[w]; tm_total += s_tm8[w]; }
    int last_idx = max(am_total - 1, 0);
    float last_val = fmaxf(s_imv[last_idx], 1e-6f);
    float scale = fmaxf((float)tm_total - 1.0f, 0.0f) / last_val;
    __syncthreads();                                    // B3 (everyone read last_val)

    for (int i = 0; i < 4; i++) {
        int t = t0 + i;
        int valid = mmv[i];
        float vv = s_imv[t] * scale * (float)valid;
        imv_out[(size_t)b * T2_ + t] = vv;
        // softmax denominator: 6-term band around floor(vv); excluded terms < 1e-39
        int c = (int)floorf(vv);
        float Z = 0.0f;
        for (int s = c - 2; s <= c + 3; s++) {
            if (s >= 0 && s < T1_ && s_tm[s]) {
                float dd = vv - (float)s;
                Z += __expf(-DELTA_C * dd * dd);
            }
        }
        Z = fmaxf(Z, 1e-30f);
        float key = valid ? vv : 3.0e4f;                // monotone past masked tail
        float2 pk = {key, valid ? (1.0f / Z) : 0.0f};   // r = am/Z
        packed[(size_t)b * T2_ + t] = pk;
        s_imv[t] = key;                                 // key array for searches
    }
    __syncthreads();                                    // B4

    // per-phoneme band bounds: start = lower_bound(key >= s-3), end = upper_bound(key > s+3)
    {
        int s = tid;
        float lov = (float)s - 3.0f, hiv = (float)s + 3.0f;
        int lo = 0, hi = T2_;
        while (lo < hi) { int mid = (lo + hi) >> 1; if (s_imv[mid] >= lov) hi = mid; else lo = mid + 1; }
        int st = lo;
        hi = T2_;
        while (lo < hi) { int mid = (lo + hi) >> 1; if (s_imv[mid] > hiv) hi = mid; else lo = mid + 1; }
        int2 be = {st, lo};
        bounds[(size_t)b * T1_ + s] = be;
    }
}

// --- K3: one wave per 2 adjacent phonemes (bands overlap 5/6 -> halve loads).
// v2: wave split into two 32-lane halves, each owning one frame of a pair with
// float4 loads -> one contiguous 1KB VMEM instr + 2 wave-exps per 2 frames
// (was 2 instrs + 4 exps); 10-shuffle cross-half combine at the end.
// Out-of-band extra terms are exp(<-90) == 0 in fp32, so joint accumulation is exact.
__global__ __launch_bounds__(256) void pool_kernel(const float* __restrict__ mels,
                                                   const int* __restrict__ text_mask,
                                                   const float2* __restrict__ packed,
                                                   const int2* __restrict__ bounds,
                                                   float* __restrict__ aligned,
                                                   float* __restrict__ dur) {
    int wid  = (int)((blockIdx.x * blockDim.x + threadIdx.x) >> 6);
    int lane = threadIdx.x & 63;
    if (wid >= B_ * (T1_ / 2)) return;
    int b = wid >> 8, s0 = (wid & 255) * 2;
    int half = lane >> 5, hl = lane & 31;
    float fs0 = (float)s0, fs1 = fs0 + 1.0f;

    const float2* pk   = packed + (size_t)b * T2_;
    const f4v*    mel4 = (const f4v*)(mels + (size_t)b * T2_ * F_);
    int2 b0 = bounds[(size_t)b * T1_ + s0];
    int2 b1 = bounds[(size_t)b * T1_ + s0 + 1];
    int t_lo = b0.x, t_hi = b1.y;       // covers both bands (monotone)

    float ax0 = 0.f, ay0 = 0.f, az0 = 0.f, aw0 = 0.f, g0s = 0.f;
    float ax1 = 0.f, ay1 = 0.f, az1 = 0.f, aw1 = 0.f, g1s = 0.f;
    for (int t = t_lo; t < t_hi; t += 2) {
        int  tl = t + half;                 // half0 -> t, half1 -> t+1
        bool on = tl < t_hi;
        int  ts = on ? tl : t;              // safe in-band index
        float2 p = pk[ts];
        f4v    m = mel4[(size_t)ts * 32 + hl];
        float d0 = p.x - fs0, d1 = p.x - fs1;
        float g0 = on ? __expf(-DELTA_C * d0 * d0) * p.y : 0.0f;
        float g1 = on ? __expf(-DELTA_C * d1 * d1) * p.y : 0.0f;
        g0s += g0; g1s += g1;
        ax0 += g0 * m.x; ay0 += g0 * m.y; az0 += g0 * m.z; aw0 += g0 * m.w;
        ax1 += g1 * m.x; ay1 += g1 * m.y; az1 += g1 * m.z; aw1 += g1 * m.w;
    }

    // cross-half combine: both halves end with full sums
    g0s += __shfl_xor(g0s, 32, 64);
    g1s += __shfl_xor(g1s, 32, 64);
    ax0 += __shfl_xor(ax0, 32, 64);
    ay0 += __shfl_xor(ay0, 32, 64);
    az0 += __shfl_xor(az0, 32, 64);
    aw0 += __shfl_xor(aw0, 32, 64);
    ax1 += __shfl_xor(ax1, 32, 64);
    ay1 += __shfl_xor(ay1, 32, 64);
    az1 += __shfl_xor(az1, 32, 64);
    aw1 += __shfl_xor(aw1, 32, 64);

    float tm0 = (float)text_mask[(size_t)b * T1_ + s0];
    float tm1 = (float)text_mask[(size_t)b * T1_ + s0 + 1];
    float inv0 = tm0 / (g0s + EPS_C);
    float inv1 = tm1 / (g1s + EPS_C);

    // half0 writes phoneme s0, half1 writes s0+1: one contiguous 1KB store
    f4v out;
    if (half == 0) {
        out.x = ax0 * inv0; out.y = ay0 * inv0; out.z = az0 * inv0; out.w = aw0 * inv0;
    } else {
        out.x = ax1 * inv1; out.y = ay1 * inv1; out.z = az1 * inv1; out.w = aw1 * inv1;
    }
    float* obase = aligned + ((size_t)b * T1_ + s0 + half) * F_;
    ((f4v*)obase)[hl] = out;
    if (lane == 0)  dur[(size_t)b * T1_ + s0]     = g0s * tm0;
    if (lane == 32) dur[(size_t)b * T1_ + s0 + 1] = g1s * tm1;
}

extern "C" void kernel_launch(void* const* d_in, const int* in_sizes, int n_in,
                              void* d_out, int out_size, void* d_ws, size_t ws_size,
                              hipStream_t stream) {
    const float* mels      = (const float*)d_in[0];
    const float* alpha     = (const float*)d_in[1];
    const int*   mel_mask  = (const int*)d_in[2];
    const int*   text_mask = (const int*)d_in[3];

    float* out     = (float*)d_out;
    float* aligned = out;                                   // B*T1*F
    float* dur     = out + (size_t)B_ * T1_ * F_;           // B*T1
    float* imv     = dur + (size_t)B_ * T1_;                // B*T2

    float*  ws     = (float*)d_ws;                          // 512 KB + 64 KB used
    float*  act    = ws;
    float*  prop   = ws + (size_t)B_ * T2_;
    float2* packed = (float2*)(ws + 2 * (size_t)B_ * T2_);
    int2*   bounds = (int2*)(ws + 4 * (size_t)B_ * T2_);

    actprop_kernel<<<(B_ * T2_) / 16, dim3(256), 0, stream>>>(mels, alpha, mel_mask, act, prop);
    scan_kernel   <<<B_,              dim3(512), 0, stream>>>(prop, act, mel_mask, text_mask, imv, packed, bounds);
    pool_kernel   <<<(B_ * T1_ / 2) / 4, dim3(256), 0, stream>>>(mels, text_mask, packed, bounds, aligned, dur);
}